// Round 5
// baseline (13210.500 us; speedup 1.0000x reference)
//
#include <hip/hip_runtime.h>

// ---------------- problem constants ----------------
constexpr int N_ = 1024;   // ITEM_SIZE
constexpr int B_ = 64;     // BATCH
constexpr int T_ = 64;     // SEQ
constexpr int CAP = 128;   // max in-degree cap (mean ~33, max ~60)
constexpr size_t OUT0 = (size_t)B_ * T_ * N_;   // 4,194,304 f32 (outs), then B*N*S h (f32)

// ---------------- compact workspace layout (float offsets) — total ~22 MB ----------------
constexpr size_t H0o   = 0;          // h state  B*N*32 = 2,097,152 f32 (8 MB)
constexpr size_t WINTo = 2097152;    // w_in^T  [j][i] 128*64 = 8192
constexpr size_t WOUTTo= 2105344;    // w_out^T                 8192
constexpr size_t WIHTo = 2113536;    // w_ih^T  [j][g]  64*96 = 6144
constexpr size_t WHHo  = 2119680;    // w_hh row-major          3072
constexpr size_t WFCo  = 2122752;    // 32
constexpr size_t BINo  = 2122784;    // 64
constexpr size_t BOUTo = 2122848;    // 64
constexpr size_t BIHo  = 2122912;    // 96
constexpr size_t BHHo  = 2123008;    // 96
constexpr size_t BFCo  = 2123104;    // 16 (1 used)
constexpr size_t INAo  = 2123120;    // 1024
constexpr size_t OUTAo = 2124144;    // 1024
constexpr size_t CCNTo = 2125168;    // 1024 int (in-degree per node)
constexpr size_t DTFo  = 2126192;    // 16 (dtype flag int)
constexpr size_t IEMo  = 2126208;    // item_emb f32 32768
constexpr size_t REMo  = 2158976;    // resp_emb f32 65536
constexpr size_t CIDXo = 2224512;    // 1024*128 int (CSC col lists)
constexpr size_t GIBo  = 2355584;    // gi cache bf16 [b][n][96] = 6,291,456 ushort
// end = 5,501,312 floats = 22.0 MB

// ---------------- helpers ----------------
__device__ __forceinline__ float bf2f(unsigned short u) {
    union { unsigned int i; float f; } x; x.i = ((unsigned int)u) << 16; return x.f;
}
__device__ __forceinline__ unsigned short f2bf(float f) {
    union { float f; unsigned int u; } x; x.f = f;
    unsigned int u = x.u;
    return (unsigned short)((u + 0x7fffu + ((u >> 16) & 1u)) >> 16);  // RNE
}
__device__ __forceinline__ float sigm(float x) { return 1.f / (1.f + __expf(-x)); }
__device__ __forceinline__ float tanhx(float x) {
    x = fminf(15.f, fmaxf(-15.f, x));
    float e = __expf(2.f * x);
    return (e - 1.f) / (e + 1.f);
}
// dtype-generic element fetch (isbf uniform per launch)
__device__ __forceinline__ float ldg_any(const void* p, int i, int isbf) {
    return isbf ? bf2f(((const unsigned short*)p)[i]) : ((const float*)p)[i];
}

// ---------------- prep: detect input float dtype from adj bit patterns ----------------
// f32 adj words are exactly 0x00000000 / 0x3F800000 (low16 never 0x3F80).
// bf16 adj would have 1.0 elements (0x3F80) at even positions.
__global__ void k_detect(const unsigned int* __restrict__ adjw, float* __restrict__ ws)
{
    __shared__ int f;
    if (threadIdx.x == 0) f = 0;
    __syncthreads();
    int local = 0;
    for (int i = threadIdx.x; i < 524288; i += blockDim.x) {
        unsigned int w = adjw[i];
        if ((w & 0xFFFFu) == 0x3F80u) local = 1;
    }
    if (local) atomicOr(&f, 1);
    __syncthreads();
    if (threadIdx.x == 0) ((int*)(ws + DTFo))[0] = f;
}

// ---------------- prep: convert/pack weights -> f32 (transposed for shfl-matvec) -------
__global__ void k_convert(const void* __restrict__ w_in,
                          const void* __restrict__ b_in,
                          const void* __restrict__ w_out,
                          const void* __restrict__ b_out,
                          const void* __restrict__ in_a,
                          const void* __restrict__ out_a,
                          const void* __restrict__ w_ih,
                          const void* __restrict__ w_hh,
                          const void* __restrict__ b_ih,
                          const void* __restrict__ b_hh,
                          const void* __restrict__ w_fc,
                          const void* __restrict__ b_fc,
                          const void* __restrict__ item_emb,
                          const void* __restrict__ resp_emb,
                          float* __restrict__ ws)
{
    const int isbf = ((const int*)(ws + DTFo))[0];
    const int tg  = blockIdx.x * blockDim.x + threadIdx.x;
    const int tot = gridDim.x * blockDim.x;
    // winT/woutT: [j*64 + i] = w[i][j],  i<64 outputs, j<128 inputs
    for (int f = tg; f < 8192; f += tot) {
        int i = f & 63, j = f >> 6;
        ws[WINTo + f]  = ldg_any(w_in , i * 128 + j, isbf);
        ws[WOUTTo + f] = ldg_any(w_out, i * 128 + j, isbf);
    }
    // wihT: [j*96 + g] = w_ih[g][j], g<96, j<64
    for (int f = tg; f < 6144; f += tot) {
        int g = f % 96, j = f / 96;
        ws[WIHTo + f] = ldg_any(w_ih, g * 64 + j, isbf);
    }
    for (int f = tg; f < 3072; f += tot) ws[WHHo + f] = ldg_any(w_hh, f, isbf);
    for (int f = tg; f < 32;   f += tot) ws[WFCo + f] = ldg_any(w_fc, f, isbf);
    for (int f = tg; f < 64;   f += tot) { ws[BINo + f] = ldg_any(b_in, f, isbf); ws[BOUTo + f] = ldg_any(b_out, f, isbf); }
    for (int f = tg; f < 96;   f += tot) { ws[BIHo + f] = ldg_any(b_ih, f, isbf); ws[BHHo + f] = ldg_any(b_hh, f, isbf); }
    if (tg == 0) ws[BFCo] = ldg_any(b_fc, 0, isbf);
    for (int f = tg; f < 1024; f += tot) { ws[INAo + f] = ldg_any(in_a, f, isbf); ws[OUTAo + f] = ldg_any(out_a, f, isbf); }
    for (int f = tg; f < 32768; f += tot) ws[IEMo + f] = ldg_any(item_emb, f, isbf);
    for (int f = tg; f < 65536; f += tot) ws[REMo + f] = ldg_any(resp_emb, f, isbf);
}

// ---------------- prep: zero h, gi(bf16) = b_ih ----------------
__global__ void k_init(float* __restrict__ ws)
{
    const size_t tg  = (size_t)blockIdx.x * blockDim.x + threadIdx.x;
    const size_t tot = (size_t)gridDim.x * blockDim.x;
    for (size_t i = tg; i < 2097152u; i += tot) ws[H0o + i] = 0.f;
    const float* bih = ws + BIHo;
    unsigned short* gib = (unsigned short*)(ws + GIBo);
    for (size_t i = tg; i < 6291456u; i += tot) {
        int g = (int)(i % 96);            // [b][n][g]
        gib[i] = f2bf(bih[g]);
    }
}

// ---------------- prep: build CSC adjacency (in-neighbor lists) ----------------
__global__ void k_csc(const void* __restrict__ adj, float* __restrict__ ws)
{
    const int isbf = ((const int*)(ws + DTFo))[0];
    const int v = blockIdx.x;          // column (dst node)
    const int lane = threadIdx.x;      // 0..63
    int* ccnt = (int*)(ws + CCNTo);
    int* cidx = (int*)(ws + CIDXo);
    int cnt = 0;
    for (int ch = 0; ch < 16; ++ch) {
        int row = ch * 64 + lane;
        bool nz;
        if (isbf) nz = (((const unsigned short*)adj)[row * 1024 + v] != 0);
        else      nz = (((const float*)adj)[row * 1024 + v] != 0.f);
        unsigned long long m = __ballot(nz);
        int pos = cnt + __popcll(m & ((1ull << lane) - 1ull));
        if (nz && pos < CAP) cidx[v * CAP + pos] = row;
        cnt += __popcll(m);
    }
    if (lane == 0) ccnt[v] = (cnt > CAP) ? CAP : cnt;
}

// ---------------- main: one persistent block per batch, full T loop ----------------
// Phase A: one wave per dst node, self-contained (shfl-broadcast matvecs).
// OUTPUT IS FLOAT32 (proven round 4: error >1 impossible under bf16 decode).
__global__ __launch_bounds__(512) void gkt_main(
    const int* __restrict__ item_ids, const int* __restrict__ responses,
    float* ws, float* __restrict__ out)
{
    const int tid  = threadIdx.x;
    const int lane = tid & 63;
    const int wave = tid >> 6;         // 0..7
    const int b    = blockIdx.x;

    float* Hb = ws + H0o + (size_t)b * 32768;                                // [n][32] f32
    unsigned short* GIb = (unsigned short*)(ws + GIBo) + (size_t)b * 98304;  // [n][96] bf16
    const float* __restrict__ winT  = ws + WINTo;
    const float* __restrict__ woutT = ws + WOUTTo;
    const float* __restrict__ wihT  = ws + WIHTo;
    const float* __restrict__ whh   = ws + WHHo;
    const float* __restrict__ wfc   = ws + WFCo;
    const float* __restrict__ bin_f = ws + BINo;
    const float* __restrict__ bout_f= ws + BOUTo;
    const float* __restrict__ bih_f = ws + BIHo;
    const float* __restrict__ bhh_f = ws + BHHo;
    const float* __restrict__ ina_f = ws + INAo;
    const float* __restrict__ outa_f= ws + OUTAo;
    const float* __restrict__ iem   = ws + IEMo;
    const float* __restrict__ rem   = ws + REMo;
    const int* __restrict__ ccnt = (const int*)(ws + CCNTo);
    const int* __restrict__ cidx = (const int*)(ws + CIDXo);

    __shared__ int dlist_s[CAP];

    for (int t = 0; t < T_; ++t) {
        const int item = item_ids[b * T_ + t];
        const int resp = responses[b * T_ + t];
        const int ndst = ccnt[item];

        for (int i = tid; i < ndst; i += 512) dlist_s[i] = cidx[item * CAP + i];
        __syncthreads();

        const float respv = (lane >= 32) ? rem[resp * 32 + (lane - 32)] : 0.f;

        // ---- phase A: one wave per dst node ----
        const int nrounds = (ndst + 7) >> 3;
        for (int r = 0; r < nrounds; ++r) {
            const int dd = r * 8 + wave;            // wave-uniform predicate
            if (dd < ndst) {
                const int v = dlist_s[dd];
                // lane holds own = h_[v][lane] (h | merged), agg = src_fea[v][lane]
                float own, agg = 0.f;
                if (lane < 32) own = Hb[v * 32 + lane];
                else           own = (v == item) ? respv : iem[v * 32 + (lane - 32)];
                const int cv = ccnt[v];
                const int* cl = cidx + v * CAP;
                for (int k = 0; k < cv; ++k) {
                    const int u = cl[k];
                    if (lane < 32) agg += Hb[u * 32 + lane];
                    else           agg += (u == item) ? respv : iem[u * 32 + (lane - 32)];
                }
                // in_fea/out_fea via shfl broadcast: lane computes output [lane] of each
                float ain = 0.f, aout = 0.f;
                #pragma unroll 8
                for (int j = 0; j < 64; ++j) {
                    const float fv = __shfl(own, j, 64);           // fea[j]
                    ain  += fv * winT [j * 64 + lane];
                    aout += fv * woutT[j * 64 + lane];
                }
                #pragma unroll 8
                for (int j = 0; j < 64; ++j) {
                    const float fv = __shfl(agg, j, 64);           // fea[64+j]
                    ain  += fv * winT [(64 + j) * 64 + lane];
                    aout += fv * woutT[(64 + j) * 64 + lane];
                }
                ain  += bin_f[lane];
                aout += bout_f[lane];
                const float dstv = outa_f[v] * aout + ina_f[v] * ain;  // dst_fea[v][lane]
                // gi[v][g] = b_ih[g] + sum_j dst_fea[j] * w_ih[g][j]
                float g0 = bih_f[lane];
                float g1 = (lane < 32) ? bih_f[64 + lane] : 0.f;
                #pragma unroll 8
                for (int j = 0; j < 64; ++j) {
                    const float dv = __shfl(dstv, j, 64);
                    g0 += dv * wihT[j * 96 + lane];
                    if (lane < 32) g1 += dv * wihT[j * 96 + 64 + lane];
                }
                unsigned short* grow = GIb + (size_t)v * 96;
                grow[lane] = f2bf(g0);
                if (lane < 32) grow[64 + lane] = f2bf(g1);
            }
        }
        __threadfence_block();
        __syncthreads();

        // ---- phase B: GRU over all nodes (2 nodes per thread) ----
        for (int rep = 0; rep < 2; ++rep) {
            const int n_l = tid + rep * 512;
            float4 h4[8];
            {
                const float4* hrow = (const float4*)(Hb + (size_t)n_l * 32);
                #pragma unroll
                for (int j = 0; j < 8; ++j) h4[j] = hrow[j];
            }
            // load gi row: 96 bf16 = 192 bytes = 12 x uint4  (round-4 bug: was 6 -> OOB UB)
            uint4 gv4[12];
            {
                const uint4* gp = (const uint4*)(GIb + (size_t)n_l * 96);
                #pragma unroll
                for (int j = 0; j < 12; ++j) gv4[j] = gp[j];
            }
            const unsigned int* gwords = (const unsigned int*)gv4;  // 48 words, 2 bf16 each
            float4 hw4[8];
            float oacc = ws[BFCo];
            #pragma unroll
            for (int j = 0; j < 8; ++j) {
                #pragma unroll
                for (int c = 0; c < 4; ++c) {
                    const int k = 4 * j + c;
                    const float4* wr4 = (const float4*)(whh + k * 32);
                    const float4* wz4 = (const float4*)(whh + (32 + k) * 32);
                    const float4* wn4 = (const float4*)(whh + (64 + k) * 32);
                    float hrv = bhh_f[k], hzv = bhh_f[32 + k], hnv = bhh_f[64 + k];
                    #pragma unroll
                    for (int s4 = 0; s4 < 8; ++s4) {
                        float4 w1 = wr4[s4], w2 = wz4[s4], w3 = wn4[s4];
                        float4 hh = h4[s4];
                        hrv += w1.x * hh.x + w1.y * hh.y + w1.z * hh.z + w1.w * hh.w;
                        hzv += w2.x * hh.x + w2.y * hh.y + w2.z * hh.z + w2.w * hh.w;
                        hnv += w3.x * hh.x + w3.y * hh.y + w3.z * hh.z + w3.w * hh.w;
                    }
                    // gi gates: ir=g[k], iz=g[32+k], in=g[64+k]
                    const unsigned int ur = gwords[k >> 1];
                    const unsigned int uz = gwords[(32 + k) >> 1];
                    const unsigned int un = gwords[(64 + k) >> 1];
                    const float gir = bf2f((k & 1) ? (unsigned short)(ur >> 16) : (unsigned short)(ur & 0xFFFF));
                    const float giz = bf2f((k & 1) ? (unsigned short)(uz >> 16) : (unsigned short)(uz & 0xFFFF));
                    const float gin = bf2f((k & 1) ? (unsigned short)(un >> 16) : (unsigned short)(un & 0xFFFF));
                    float r  = sigm(gir + hrv);
                    float z  = sigm(giz + hzv);
                    float nn = tanhx(gin + r * hnv);
                    float hp = ((const float*)&h4[j])[c];
                    float hv = (1.f - z) * nn + z * hp;
                    ((float*)&hw4[j])[c] = hv;
                    oacc += hv * wfc[k];
                }
            }
            {
                float4* hwrow = (float4*)(Hb + (size_t)n_l * 32);
                #pragma unroll
                for (int j = 0; j < 8; ++j) hwrow[j] = hw4[j];
            }
            out[(size_t)b * 65536 + (size_t)t * 1024 + n_l] = sigm(oacc);     // f32 store
            if (t == T_ - 1) {
                float4* ho = (float4*)(out + OUT0 + (size_t)b * 32768 + (size_t)n_l * 32);
                #pragma unroll
                for (int j = 0; j < 8; ++j) ho[j] = hw4[j];                   // f32 h state
            }
        }
        __threadfence_block();
        __syncthreads();   // h/gi writes visible before next step's phase A
    }
}

extern "C" void kernel_launch(void* const* d_in, const int* in_sizes, int n_in,
                              void* d_out, int out_size, void* d_ws, size_t ws_size,
                              hipStream_t stream)
{
    (void)in_sizes; (void)n_in; (void)out_size; (void)ws_size;
    const int* item_ids  = (const int*)d_in[0];
    const int* responses = (const int*)d_in[1];
    const void* adj      = d_in[2];
    const void* item_emb = d_in[3];
    const void* resp_emb = d_in[4];
    const void* w_in  = d_in[5];
    const void* b_in  = d_in[6];
    const void* w_out = d_in[7];
    const void* b_out = d_in[8];
    const void* in_a  = d_in[9];
    const void* out_a = d_in[10];
    const void* w_ih  = d_in[11];
    const void* w_hh  = d_in[12];
    const void* b_ih  = d_in[13];
    const void* b_hh  = d_in[14];
    const void* w_fc  = d_in[15];
    const void* b_fc  = d_in[16];
    float* ws = (float*)d_ws;
    float* out = (float*)d_out;

    k_detect<<<dim3(1), dim3(1024), 0, stream>>>((const unsigned int*)adj, ws);
    k_convert<<<dim3(64), dim3(256), 0, stream>>>(w_in, b_in, w_out, b_out, in_a, out_a,
                                                  w_ih, w_hh, b_ih, b_hh, w_fc, b_fc,
                                                  item_emb, resp_emb, ws);
    k_init<<<dim3(512), dim3(256), 0, stream>>>(ws);
    k_csc<<<dim3(1024), dim3(64), 0, stream>>>(adj, ws);
    gkt_main<<<dim3(64), dim3(512), 0, stream>>>(item_ids, responses, ws, out);
}

// Round 6
// 7797.845 us; speedup vs baseline: 1.6941x; 1.6941x over previous
//
#include <hip/hip_runtime.h>

// ---------------- problem constants ----------------
constexpr int N_ = 1024;   // ITEM_SIZE
constexpr int B_ = 64;     // BATCH
constexpr int T_ = 64;     // SEQ
constexpr int CAP = 128;   // max in-degree cap (mean ~33, max ~60)
constexpr size_t OUT0 = (size_t)B_ * T_ * N_;   // 4,194,304 f32 (outs), then B*N*S h (f32)

// ---------------- compact workspace layout (float offsets) — total ~22 MB ----------------
constexpr size_t H0o   = 0;          // (unused now; h lives in LDS)
constexpr size_t WINTo = 2097152;    // w_in^T  [j][i] 128*64 = 8192
constexpr size_t WOUTTo= 2105344;    // w_out^T                 8192
constexpr size_t WIHTo = 2113536;    // w_ih^T  [j][g]  64*96 = 6144
constexpr size_t WHHo  = 2119680;    // w_hh row-major          3072
constexpr size_t WFCo  = 2122752;    // 32
constexpr size_t BINo  = 2122784;    // 64
constexpr size_t BOUTo = 2122848;    // 64
constexpr size_t BIHo  = 2122912;    // 96
constexpr size_t BHHo  = 2123008;    // 96
constexpr size_t BFCo  = 2123104;    // 16 (1 used)
constexpr size_t INAo  = 2123120;    // 1024
constexpr size_t OUTAo = 2124144;    // 1024
constexpr size_t CCNTo = 2125168;    // 1024 int (in-degree per node)
constexpr size_t DTFo  = 2126192;    // 16 (dtype flag int)
constexpr size_t IEMo  = 2126208;    // item_emb f32 32768
constexpr size_t REMo  = 2158976;    // resp_emb f32 65536
constexpr size_t CIDXo = 2224512;    // 1024*128 int (CSC col lists)
constexpr size_t GIBo  = 2355584;    // gi cache bf16 [b][n][96] = 6,291,456 ushort
// end = 5,501,312 floats = 22.0 MB

// LDS layout (floats): h[32768] | fea_stage[8*192] | dlist[128 ints]
constexpr int LDS_FEA  = 32768;
constexpr int LDS_DLIST= 32768 + 8 * 192;          // 34304
constexpr int LDS_BYTES= (34304 + 128) * 4;        // 137,728 B

// ---------------- helpers ----------------
__device__ __forceinline__ float bf2f(unsigned short u) {
    union { unsigned int i; float f; } x; x.i = ((unsigned int)u) << 16; return x.f;
}
__device__ __forceinline__ unsigned short f2bf(float f) {
    union { float f; unsigned int u; } x; x.f = f;
    unsigned int u = x.u;
    return (unsigned short)((u + 0x7fffu + ((u >> 16) & 1u)) >> 16);  // RNE
}
__device__ __forceinline__ float sigm(float x) { return 1.f / (1.f + __expf(-x)); }
__device__ __forceinline__ float tanhx(float x) {
    x = fminf(15.f, fmaxf(-15.f, x));
    float e = __expf(2.f * x);
    return (e - 1.f) / (e + 1.f);
}
__device__ __forceinline__ float ldg_any(const void* p, int i, int isbf) {
    return isbf ? bf2f(((const unsigned short*)p)[i]) : ((const float*)p)[i];
}

// ---------------- prep: detect input float dtype from adj bit patterns ----------------
__global__ void k_detect(const unsigned int* __restrict__ adjw, float* __restrict__ ws)
{
    __shared__ int f;
    if (threadIdx.x == 0) f = 0;
    __syncthreads();
    int local = 0;
    for (int i = threadIdx.x; i < 524288; i += blockDim.x) {
        unsigned int w = adjw[i];
        if ((w & 0xFFFFu) == 0x3F80u) local = 1;
    }
    if (local) atomicOr(&f, 1);
    __syncthreads();
    if (threadIdx.x == 0) ((int*)(ws + DTFo))[0] = f;
}

// ---------------- prep: convert/pack weights -> f32 ----------------
__global__ void k_convert(const void* __restrict__ w_in,
                          const void* __restrict__ b_in,
                          const void* __restrict__ w_out,
                          const void* __restrict__ b_out,
                          const void* __restrict__ in_a,
                          const void* __restrict__ out_a,
                          const void* __restrict__ w_ih,
                          const void* __restrict__ w_hh,
                          const void* __restrict__ b_ih,
                          const void* __restrict__ b_hh,
                          const void* __restrict__ w_fc,
                          const void* __restrict__ b_fc,
                          const void* __restrict__ item_emb,
                          const void* __restrict__ resp_emb,
                          float* __restrict__ ws)
{
    const int isbf = ((const int*)(ws + DTFo))[0];
    const int tg  = blockIdx.x * blockDim.x + threadIdx.x;
    const int tot = gridDim.x * blockDim.x;
    for (int f = tg; f < 8192; f += tot) {
        int i = f & 63, j = f >> 6;
        ws[WINTo + f]  = ldg_any(w_in , i * 128 + j, isbf);
        ws[WOUTTo + f] = ldg_any(w_out, i * 128 + j, isbf);
    }
    for (int f = tg; f < 6144; f += tot) {
        int g = f % 96, j = f / 96;
        ws[WIHTo + f] = ldg_any(w_ih, g * 64 + j, isbf);
    }
    for (int f = tg; f < 3072; f += tot) ws[WHHo + f] = ldg_any(w_hh, f, isbf);
    for (int f = tg; f < 32;   f += tot) ws[WFCo + f] = ldg_any(w_fc, f, isbf);
    for (int f = tg; f < 64;   f += tot) { ws[BINo + f] = ldg_any(b_in, f, isbf); ws[BOUTo + f] = ldg_any(b_out, f, isbf); }
    for (int f = tg; f < 96;   f += tot) { ws[BIHo + f] = ldg_any(b_ih, f, isbf); ws[BHHo + f] = ldg_any(b_hh, f, isbf); }
    if (tg == 0) ws[BFCo] = ldg_any(b_fc, 0, isbf);
    for (int f = tg; f < 1024; f += tot) { ws[INAo + f] = ldg_any(in_a, f, isbf); ws[OUTAo + f] = ldg_any(out_a, f, isbf); }
    for (int f = tg; f < 32768; f += tot) ws[IEMo + f] = ldg_any(item_emb, f, isbf);
    for (int f = tg; f < 65536; f += tot) ws[REMo + f] = ldg_any(resp_emb, f, isbf);
}

// ---------------- prep: gi(bf16) = b_ih ----------------
__global__ void k_init(float* __restrict__ ws)
{
    const size_t tg  = (size_t)blockIdx.x * blockDim.x + threadIdx.x;
    const size_t tot = (size_t)gridDim.x * blockDim.x;
    const float* bih = ws + BIHo;
    unsigned short* gib = (unsigned short*)(ws + GIBo);
    for (size_t i = tg; i < 6291456u; i += tot) {
        int g = (int)(i % 96);            // [b][n][g]
        gib[i] = f2bf(bih[g]);
    }
}

// ---------------- prep: build CSC adjacency (in-neighbor lists) ----------------
__global__ void k_csc(const void* __restrict__ adj, float* __restrict__ ws)
{
    const int isbf = ((const int*)(ws + DTFo))[0];
    const int v = blockIdx.x;
    const int lane = threadIdx.x;
    int* ccnt = (int*)(ws + CCNTo);
    int* cidx = (int*)(ws + CIDXo);
    int cnt = 0;
    for (int ch = 0; ch < 16; ++ch) {
        int row = ch * 64 + lane;
        bool nz;
        if (isbf) nz = (((const unsigned short*)adj)[row * 1024 + v] != 0);
        else      nz = (((const float*)adj)[row * 1024 + v] != 0.f);
        unsigned long long m = __ballot(nz);
        int pos = cnt + __popcll(m & ((1ull << lane) - 1ull));
        if (nz && pos < CAP) cidx[v * CAP + pos] = row;
        cnt += __popcll(m);
    }
    if (lane == 0) ccnt[v] = (cnt > CAP) ? CAP : cnt;
}

// ---------------- main: one persistent block per batch, h in LDS ----------------
__global__ __launch_bounds__(512, 2) void gkt_main(
    const int* __restrict__ item_ids, const int* __restrict__ responses,
    float* ws, float* __restrict__ out)
{
    extern __shared__ float smem[];
    float* h_lds = smem;                                  // [1024][32] f32
    float* fea_stage = smem + LDS_FEA;                    // [8][192]
    int*   dlist_s = (int*)(smem + LDS_DLIST);            // [128]

    const int tid  = threadIdx.x;
    const int lane = tid & 63;
    const int wave = tid >> 6;         // 0..7
    const int b    = blockIdx.x;
    const int s    = lane & 31;
    const int gsel = (lane >> 5) & 1;  // group within wave

    unsigned short* GIb = (unsigned short*)(ws + GIBo) + (size_t)b * 98304;  // [n][96] bf16
    const float* __restrict__ winT  = ws + WINTo;
    const float* __restrict__ woutT = ws + WOUTTo;
    const float* __restrict__ wihT  = ws + WIHTo;
    const float* __restrict__ whh   = ws + WHHo;
    const float* __restrict__ bin_f = ws + BINo;
    const float* __restrict__ bout_f= ws + BOUTo;
    const float* __restrict__ bih_f = ws + BIHo;
    const float* __restrict__ bhh_f = ws + BHHo;
    const float* __restrict__ ina_f = ws + INAo;
    const float* __restrict__ outa_f= ws + OUTAo;
    const float* __restrict__ iem   = ws + IEMo;
    const float* __restrict__ rem   = ws + REMo;
    const int* __restrict__ ccnt = (const int*)(ws + CCNTo);
    const int* __restrict__ cidx = (const int*)(ws + CIDXo);

    // zero h
    for (int i = tid; i < 32768; i += 512) h_lds[i] = 0.f;

    // register-stationary GRU recurrent weights for this lane's state index s
    float wr[32], wz[32], wn[32];
    #pragma unroll
    for (int j = 0; j < 32; ++j) {
        wr[j] = whh[s * 32 + j];
        wz[j] = whh[(32 + s) * 32 + j];
        wn[j] = whh[(64 + s) * 32 + j];
    }
    const float bhr = bhh_f[s], bhz = bhh_f[32 + s], bhn = bhh_f[64 + s];
    const float wfcs = ws[WFCo + s];
    const float bfc  = ws[BFCo];
    __syncthreads();

    for (int t = 0; t < T_; ++t) {
        const int item = item_ids[b * T_ + t];
        const int resp = responses[b * T_ + t];
        const int ndst = ccnt[item];

        for (int i = tid; i < ndst; i += 512) dlist_s[i] = cidx[item * CAP + i];
        __syncthreads();

        const float respv = (lane >= 32) ? rem[resp * 32 + (lane - 32)] : 0.f;

        // ---- phase A: one wave per dst node; matvecs via LDS-broadcast float4 ----
        float* fstage = fea_stage + wave * 192;
        const int nrounds = (ndst + 7) >> 3;
        for (int r = 0; r < nrounds; ++r) {
            const int dd = r * 8 + wave;            // wave-uniform predicate
            if (dd < ndst) {
                const int v = dlist_s[dd];
                // fea: lane -> own = h_|merged, agg = sum over in-neighbors
                float own, agg = 0.f;
                if (lane < 32) own = h_lds[v * 32 + lane];
                else           own = (v == item) ? respv : iem[v * 32 + (lane - 32)];
                const int cv = ccnt[v];
                const int* cl = cidx + v * CAP;
                #pragma unroll 4
                for (int k = 0; k < cv; ++k) {
                    const int u = cl[k];
                    if (lane < 32) agg += h_lds[u * 32 + lane];
                    else           agg += (u == item) ? respv : iem[u * 32 + (lane - 32)];
                }
                fstage[lane]      = own;   // fea[0..63]
                fstage[64 + lane] = agg;   // fea[64..127]
                // FC: lane computes in_fea[lane], out_fea[lane]
                float ain = 0.f, aout = 0.f;
                const float4* f4p = (const float4*)fstage;    // 32 float4, broadcast reads
                #pragma unroll 8
                for (int c = 0; c < 32; ++c) {
                    const float4 f = f4p[c];
                    ain  += f.x * winT [(4*c+0)*64 + lane] + f.y * winT [(4*c+1)*64 + lane]
                          + f.z * winT [(4*c+2)*64 + lane] + f.w * winT [(4*c+3)*64 + lane];
                    aout += f.x * woutT[(4*c+0)*64 + lane] + f.y * woutT[(4*c+1)*64 + lane]
                          + f.z * woutT[(4*c+2)*64 + lane] + f.w * woutT[(4*c+3)*64 + lane];
                }
                ain  += bin_f[lane];
                aout += bout_f[lane];
                const float dstv = outa_f[v] * aout + ina_f[v] * ain;
                fstage[128 + lane] = dstv;
                // gi[v][g] = b_ih[g] + dst_fea . w_ih[g]
                float g0 = bih_f[lane];
                float g1 = (lane < 32) ? bih_f[64 + lane] : 0.f;
                const float4* d4p = (const float4*)(fstage + 128); // 16 float4
                #pragma unroll 8
                for (int c = 0; c < 16; ++c) {
                    const float4 dv = d4p[c];
                    g0 += dv.x * wihT[(4*c+0)*96 + lane] + dv.y * wihT[(4*c+1)*96 + lane]
                        + dv.z * wihT[(4*c+2)*96 + lane] + dv.w * wihT[(4*c+3)*96 + lane];
                    if (lane < 32) {
                        g1 += dv.x * wihT[(4*c+0)*96 + 64 + lane] + dv.y * wihT[(4*c+1)*96 + 64 + lane]
                            + dv.z * wihT[(4*c+2)*96 + 64 + lane] + dv.w * wihT[(4*c+3)*96 + 64 + lane];
                    }
                }
                unsigned short* grow = GIb + (size_t)v * 96;
                grow[lane] = f2bf(g0);
                if (lane < 32) grow[64 + lane] = f2bf(g1);
            }
        }
        __threadfence_block();
        __syncthreads();

        // ---- phase B: GRU; wave handles 128 nodes (2 at a time, one per 32-lane group) ----
        {
            int n = wave * 128 + gsel;
            const unsigned short* gp = GIb + (size_t)n * 96;
            unsigned short curS = gp[s], cur32 = gp[32 + s], cur64 = gp[64 + s];
            for (int i = 0; i < 64; ++i, n += 2) {
                // prefetch next node's gi trio
                unsigned short nxS = 0, nx32 = 0, nx64 = 0;
                if (i < 63) {
                    const unsigned short* gn = GIb + (size_t)(n + 2) * 96;
                    nxS = gn[s]; nx32 = gn[32 + s]; nx64 = gn[64 + s];
                }
                // broadcast h row (same addr within group -> conflict-free)
                const float4* hrow = (const float4*)(h_lds + n * 32);
                float4 hh[8];
                #pragma unroll
                for (int q = 0; q < 8; ++q) hh[q] = hrow[q];
                const float h_own = h_lds[n * 32 + s];
                float ar = bhr, az = bhz, an = bhn;
                const float* hf = (const float*)hh;
                #pragma unroll
                for (int j = 0; j < 32; ++j) {
                    const float hv = hf[j];
                    ar += wr[j] * hv; az += wz[j] * hv; an += wn[j] * hv;
                }
                const float gir = bf2f(curS), giz = bf2f(cur32), gin = bf2f(cur64);
                const float rg = sigm(gir + ar);
                const float zg = sigm(giz + az);
                const float ng = tanhx(gin + rg * an);
                const float hv2 = (1.f - zg) * ng + zg * h_own;
                h_lds[n * 32 + s] = hv2;
                float red = hv2 * wfcs;
                red += __shfl_xor(red, 16); red += __shfl_xor(red, 8);
                red += __shfl_xor(red, 4);  red += __shfl_xor(red, 2);
                red += __shfl_xor(red, 1);
                if (s == 0) out[(size_t)b * 65536 + (size_t)t * 1024 + n] = sigm(red + bfc);
                if (t == T_ - 1) out[OUT0 + (size_t)b * 32768 + (size_t)n * 32 + s] = hv2;
                curS = nxS; cur32 = nx32; cur64 = nx64;
            }
        }
        __threadfence_block();
        __syncthreads();   // h/gi writes visible before next step's phase A
    }
}

extern "C" void kernel_launch(void* const* d_in, const int* in_sizes, int n_in,
                              void* d_out, int out_size, void* d_ws, size_t ws_size,
                              hipStream_t stream)
{
    (void)in_sizes; (void)n_in; (void)out_size; (void)ws_size;
    const int* item_ids  = (const int*)d_in[0];
    const int* responses = (const int*)d_in[1];
    const void* adj      = d_in[2];
    const void* item_emb = d_in[3];
    const void* resp_emb = d_in[4];
    const void* w_in  = d_in[5];
    const void* b_in  = d_in[6];
    const void* w_out = d_in[7];
    const void* b_out = d_in[8];
    const void* in_a  = d_in[9];
    const void* out_a = d_in[10];
    const void* w_ih  = d_in[11];
    const void* w_hh  = d_in[12];
    const void* b_ih  = d_in[13];
    const void* b_hh  = d_in[14];
    const void* w_fc  = d_in[15];
    const void* b_fc  = d_in[16];
    float* ws = (float*)d_ws;
    float* out = (float*)d_out;

    static int attr_done = 0;
    (void)hipFuncSetAttribute((const void*)gkt_main,
                              hipFuncAttributeMaxDynamicSharedMemorySize, LDS_BYTES);
    attr_done = 1; (void)attr_done;

    k_detect<<<dim3(1), dim3(1024), 0, stream>>>((const unsigned int*)adj, ws);
    k_convert<<<dim3(64), dim3(256), 0, stream>>>(w_in, b_in, w_out, b_out, in_a, out_a,
                                                  w_ih, w_hh, b_ih, b_hh, w_fc, b_fc,
                                                  item_emb, resp_emb, ws);
    k_init<<<dim3(512), dim3(256), 0, stream>>>(ws);
    k_csc<<<dim3(1024), dim3(64), 0, stream>>>(adj, ws);
    gkt_main<<<dim3(64), dim3(512), LDS_BYTES, stream>>>(item_ids, responses, ws, out);
}

// Round 8
// 5586.936 us; speedup vs baseline: 2.3645x; 1.3957x over previous
//
#include <hip/hip_runtime.h>

// ---------------- problem constants ----------------
constexpr int N_ = 1024;   // ITEM_SIZE
constexpr int B_ = 64;     // BATCH
constexpr int T_ = 64;     // SEQ
constexpr int CAP = 128;   // max in-degree cap (mean ~33, max ~60)
constexpr size_t OUT0 = (size_t)B_ * T_ * N_;   // 4,194,304 f32 (outs), then B*N*S h (f32)

// ---------------- workspace layout (float offsets) ----------------
constexpr size_t H0o   = 0;          // h state  B*N*32 = 2,097,152 f32
constexpr size_t WINTo = 2097152;    // w_in^T  [j][i] 128*64 = 8192
constexpr size_t WOUTTo= 2105344;    // w_out^T                 8192
constexpr size_t WIHTo = 2113536;    // w_ih^T  [j][g]  64*96 = 6144
constexpr size_t WHHo  = 2119680;    // w_hh row-major          3072
constexpr size_t WFCo  = 2122752;    // 32
constexpr size_t BINo  = 2122784;    // 64
constexpr size_t BOUTo = 2122848;    // 64
constexpr size_t BIHo  = 2122912;    // 96
constexpr size_t BHHo  = 2123008;    // 96
constexpr size_t BFCo  = 2123104;    // 16 (1 used)
constexpr size_t INAo  = 2123120;    // 1024
constexpr size_t OUTAo = 2124144;    // 1024
constexpr size_t CCNTo = 2125168;    // 1024 int (in-degree per node)
constexpr size_t DTFo  = 2126192;    // 16 (dtype flag int)
constexpr size_t IEMo  = 2126208;    // item_emb f32 32768
constexpr size_t REMo  = 2158976;    // resp_emb f32 65536
constexpr size_t CIDXo = 2224512;    // 1024*128 int (CSC col lists)
constexpr size_t GIBo  = 2355584;    // gi cache bf16 [b][n][96] = 6,291,456 ushort
constexpr size_t BARo  = 5501312;    // 64 ints: per-batch epoch barrier counters
// end = 5,501,376 floats ~= 22.005 MB

// ---------------- helpers ----------------
__device__ __forceinline__ float bf2f(unsigned short u) {
    union { unsigned int i; float f; } x; x.i = ((unsigned int)u) << 16; return x.f;
}
__device__ __forceinline__ unsigned short f2bf(float f) {
    union { float f; unsigned int u; } x; x.f = f;
    unsigned int u = x.u;
    return (unsigned short)((u + 0x7fffu + ((u >> 16) & 1u)) >> 16);  // RNE
}
__device__ __forceinline__ float sigm(float x) { return 1.f / (1.f + __expf(-x)); }
__device__ __forceinline__ float tanhx(float x) {
    x = fminf(15.f, fmaxf(-15.f, x));
    float e = __expf(2.f * x);
    return (e - 1.f) / (e + 1.f);
}
__device__ __forceinline__ float ldg_any(const void* p, int i, int isbf) {
    return isbf ? bf2f(((const unsigned short*)p)[i]) : ((const float*)p)[i];
}

// 4-block per-batch epoch barrier.
// ROUND-7 BUG FIX: must __syncthreads() BEFORE tid0 signals, so all waves' global
// stores are issued+drained (s_barrier implies vmcnt(0) drain) before we publish.
__device__ __forceinline__ void bar4(int* c, int& ep, int tid) {
    __syncthreads();                       // all block stores drained to L2
    if (tid == 0) {
        __threadfence();                   // device-scope publish of this CU's writes
        __hip_atomic_fetch_add(c, 1, __ATOMIC_RELEASE, __HIP_MEMORY_SCOPE_AGENT);
        const int target = 4 * (++ep);
        while (__hip_atomic_load(c, __ATOMIC_ACQUIRE, __HIP_MEMORY_SCOPE_AGENT) < target)
            __builtin_amdgcn_s_sleep(2);
        __threadfence();                   // acquire: invalidate stale cached lines
    } else {
        ++ep;
    }
    __syncthreads();
}

// ---------------- prep: detect input float dtype from adj bit patterns ----------------
__global__ void k_detect(const unsigned int* __restrict__ adjw, float* __restrict__ ws)
{
    __shared__ int f;
    if (threadIdx.x == 0) f = 0;
    __syncthreads();
    int local = 0;
    for (int i = threadIdx.x; i < 524288; i += blockDim.x) {
        unsigned int w = adjw[i];
        if ((w & 0xFFFFu) == 0x3F80u) local = 1;
    }
    if (local) atomicOr(&f, 1);
    __syncthreads();
    if (threadIdx.x == 0) ((int*)(ws + DTFo))[0] = f;
}

// ---------------- prep: convert/pack weights -> f32 ----------------
__global__ void k_convert(const void* __restrict__ w_in,  const void* __restrict__ b_in,
                          const void* __restrict__ w_out, const void* __restrict__ b_out,
                          const void* __restrict__ in_a,  const void* __restrict__ out_a,
                          const void* __restrict__ w_ih,  const void* __restrict__ w_hh,
                          const void* __restrict__ b_ih,  const void* __restrict__ b_hh,
                          const void* __restrict__ w_fc,  const void* __restrict__ b_fc,
                          const void* __restrict__ item_emb, const void* __restrict__ resp_emb,
                          float* __restrict__ ws)
{
    const int isbf = ((const int*)(ws + DTFo))[0];
    const int tg  = blockIdx.x * blockDim.x + threadIdx.x;
    const int tot = gridDim.x * blockDim.x;
    for (int f = tg; f < 8192; f += tot) {
        int i = f & 63, j = f >> 6;
        ws[WINTo + f]  = ldg_any(w_in , i * 128 + j, isbf);
        ws[WOUTTo + f] = ldg_any(w_out, i * 128 + j, isbf);
    }
    for (int f = tg; f < 6144; f += tot) {
        int g = f % 96, j = f / 96;
        ws[WIHTo + f] = ldg_any(w_ih, g * 64 + j, isbf);
    }
    for (int f = tg; f < 3072; f += tot) ws[WHHo + f] = ldg_any(w_hh, f, isbf);
    for (int f = tg; f < 32;   f += tot) ws[WFCo + f] = ldg_any(w_fc, f, isbf);
    for (int f = tg; f < 64;   f += tot) { ws[BINo + f] = ldg_any(b_in, f, isbf); ws[BOUTo + f] = ldg_any(b_out, f, isbf); }
    for (int f = tg; f < 96;   f += tot) { ws[BIHo + f] = ldg_any(b_ih, f, isbf); ws[BHHo + f] = ldg_any(b_hh, f, isbf); }
    if (tg == 0) ws[BFCo] = ldg_any(b_fc, 0, isbf);
    for (int f = tg; f < 1024; f += tot) { ws[INAo + f] = ldg_any(in_a, f, isbf); ws[OUTAo + f] = ldg_any(out_a, f, isbf); }
    for (int f = tg; f < 32768; f += tot) ws[IEMo + f] = ldg_any(item_emb, f, isbf);
    for (int f = tg; f < 65536; f += tot) ws[REMo + f] = ldg_any(resp_emb, f, isbf);
}

// ---------------- prep: zero h + barrier counters, gi(bf16) = b_ih ----------------
__global__ void k_init(float* __restrict__ ws)
{
    const size_t tg  = (size_t)blockIdx.x * blockDim.x + threadIdx.x;
    const size_t tot = (size_t)gridDim.x * blockDim.x;
    for (size_t i = tg; i < 2097152u; i += tot) ws[H0o + i] = 0.f;
    if (tg < 64) ((int*)(ws + BARo))[tg] = 0;
    const float* bih = ws + BIHo;
    unsigned short* gib = (unsigned short*)(ws + GIBo);
    for (size_t i = tg; i < 6291456u; i += tot) {
        int g = (int)(i % 96);            // [b][n][g]
        gib[i] = f2bf(bih[g]);
    }
}

// ---------------- prep: build CSC adjacency (in-neighbor lists) ----------------
__global__ void k_csc(const void* __restrict__ adj, float* __restrict__ ws)
{
    const int isbf = ((const int*)(ws + DTFo))[0];
    const int v = blockIdx.x;
    const int lane = threadIdx.x;
    int* ccnt = (int*)(ws + CCNTo);
    int* cidx = (int*)(ws + CIDXo);
    int cnt = 0;
    for (int ch = 0; ch < 16; ++ch) {
        int row = ch * 64 + lane;
        bool nz;
        if (isbf) nz = (((const unsigned short*)adj)[row * 1024 + v] != 0);
        else      nz = (((const float*)adj)[row * 1024 + v] != 0.f);
        unsigned long long m = __ballot(nz);
        int pos = cnt + __popcll(m & ((1ull << lane) - 1ull));
        if (nz && pos < CAP) cidx[v * CAP + pos] = row;
        cnt += __popcll(m);
    }
    if (lane == 0) ccnt[v] = (cnt > CAP) ? CAP : cnt;
}

// ---------------- main: 256 blocks = 4 per batch (cooperative), h in global ----------------
// blockIdx = sub*64 + b  (keeps a batch's 4 blocks on one XCD under the %8 dispatch heuristic;
// correctness does NOT depend on it — bar4 uses agent-scope acquire/release)
__global__ __launch_bounds__(512) void gkt_main(
    const int* __restrict__ item_ids, const int* __restrict__ responses,
    float* ws, float* __restrict__ out)
{
    const int tid  = threadIdx.x;
    const int lane = tid & 63;
    const int wave = tid >> 6;         // 0..7
    const int b    = blockIdx.x & 63;
    const int sub  = blockIdx.x >> 6;  // 0..3
    const int s    = lane & 31;
    const int gsel = (lane >> 5) & 1;

    float* Hb = ws + H0o + (size_t)b * 32768;                                // [n][32] f32
    unsigned short* GIb = (unsigned short*)(ws + GIBo) + (size_t)b * 98304;  // [n][96] bf16
    int* barc = (int*)(ws + BARo) + b;
    const float* __restrict__ winT  = ws + WINTo;
    const float* __restrict__ woutT = ws + WOUTTo;
    const float* __restrict__ wihT  = ws + WIHTo;
    const float* __restrict__ whh   = ws + WHHo;
    const float* __restrict__ bin_f = ws + BINo;
    const float* __restrict__ bout_f= ws + BOUTo;
    const float* __restrict__ bih_f = ws + BIHo;
    const float* __restrict__ bhh_f = ws + BHHo;
    const float* __restrict__ ina_f = ws + INAo;
    const float* __restrict__ outa_f= ws + OUTAo;
    const float* __restrict__ iem   = ws + IEMo;
    const float* __restrict__ rem   = ws + REMo;
    const int* __restrict__ ccnt = (const int*)(ws + CCNTo);
    const int* __restrict__ cidx = (const int*)(ws + CIDXo);

    __shared__ __attribute__((aligned(16))) float fea_stage[8 * 192];

    // register-stationary GRU recurrent weights for this lane's state index s
    float wr[32], wz[32], wn[32];
    #pragma unroll
    for (int j = 0; j < 32; ++j) {
        wr[j] = whh[s * 32 + j];
        wz[j] = whh[(32 + s) * 32 + j];
        wn[j] = whh[(64 + s) * 32 + j];
    }
    const float bhr = bhh_f[s], bhz = bhh_f[32 + s], bhn = bhh_f[64 + s];
    const float wfcs = ws[WFCo + s];
    const float bfc  = ws[BFCo];

    int ep = 0;
    const int gid   = wave * 2 + gsel;            // 0..15
    const int nbase = sub * 256 + gid * 16;       // phase-B node range [nbase, nbase+16)

    for (int t = 0; t < T_; ++t) {
        const int item = item_ids[b * T_ + t];
        const int resp = responses[b * T_ + t];
        const int ndst = ccnt[item];
        const float respv = (lane >= 32) ? rem[resp * 32 + (lane - 32)] : 0.f;

        // ---- phase A: this block handles dlist indices i ≡ sub (mod 4), one per wave ----
        float* fstage = fea_stage + wave * 192;
        for (int i = sub + 4 * wave; i < ndst; i += 32) {
            const int v = cidx[item * CAP + i];
            float own, agg = 0.f;
            if (lane < 32) own = Hb[v * 32 + lane];
            else           own = (v == item) ? respv : iem[v * 32 + (lane - 32)];
            const int cv = ccnt[v];
            const int* cl = cidx + v * CAP;
            #pragma unroll 4
            for (int k = 0; k < cv; ++k) {
                const int u = cl[k];
                if (lane < 32) agg += Hb[u * 32 + lane];
                else           agg += (u == item) ? respv : iem[u * 32 + (lane - 32)];
            }
            fstage[lane]      = own;
            fstage[64 + lane] = agg;
            float ain = 0.f, aout = 0.f;
            const float4* f4p = (const float4*)fstage;
            #pragma unroll 8
            for (int c = 0; c < 32; ++c) {
                const float4 f = f4p[c];
                ain  += f.x * winT [(4*c+0)*64 + lane] + f.y * winT [(4*c+1)*64 + lane]
                      + f.z * winT [(4*c+2)*64 + lane] + f.w * winT [(4*c+3)*64 + lane];
                aout += f.x * woutT[(4*c+0)*64 + lane] + f.y * woutT[(4*c+1)*64 + lane]
                      + f.z * woutT[(4*c+2)*64 + lane] + f.w * woutT[(4*c+3)*64 + lane];
            }
            ain  += bin_f[lane];
            aout += bout_f[lane];
            const float dstv = outa_f[v] * aout + ina_f[v] * ain;
            fstage[128 + lane] = dstv;
            float g0 = bih_f[lane];
            float g1 = (lane < 32) ? bih_f[64 + lane] : 0.f;
            const float4* d4p = (const float4*)(fstage + 128);
            #pragma unroll 8
            for (int c = 0; c < 16; ++c) {
                const float4 dv = d4p[c];
                g0 += dv.x * wihT[(4*c+0)*96 + lane] + dv.y * wihT[(4*c+1)*96 + lane]
                    + dv.z * wihT[(4*c+2)*96 + lane] + dv.w * wihT[(4*c+3)*96 + lane];
                if (lane < 32) {
                    g1 += dv.x * wihT[(4*c+0)*96 + 64 + lane] + dv.y * wihT[(4*c+1)*96 + 64 + lane]
                        + dv.z * wihT[(4*c+2)*96 + 64 + lane] + dv.w * wihT[(4*c+3)*96 + 64 + lane];
                }
            }
            unsigned short* grow = GIb + (size_t)v * 96;
            grow[lane] = f2bf(g0);
            if (lane < 32) grow[64 + lane] = f2bf(g1);
        }
        bar4(barc, ep, tid);   // gi complete across all 4 blocks

        // ---- phase B: GRU on nodes [nbase, nbase+16), ring-1 prefetch of gi + h row ----
        {
            int n = nbase;
            const unsigned short* gp = GIb + (size_t)n * 96;
            unsigned short cS = gp[s], c32 = gp[32 + s], c64 = gp[64 + s];
            const float4* hrow = (const float4*)(Hb + (size_t)n * 32);
            float4 ch[8];
            #pragma unroll
            for (int q = 0; q < 8; ++q) ch[q] = hrow[q];
            float h_own = Hb[(size_t)n * 32 + s];

            for (int i = 0; i < 16; ++i, ++n) {
                unsigned short nS = 0, n32 = 0, n64 = 0;
                float4 nh[8];
                float nh_own = 0.f;
                if (i < 15) {
                    const unsigned short* gn = GIb + (size_t)(n + 1) * 96;
                    nS = gn[s]; n32 = gn[32 + s]; n64 = gn[64 + s];
                    const float4* hnx = (const float4*)(Hb + (size_t)(n + 1) * 32);
                    #pragma unroll
                    for (int q = 0; q < 8; ++q) nh[q] = hnx[q];
                    nh_own = Hb[(size_t)(n + 1) * 32 + s];
                }
                float ar = bhr, az = bhz, an = bhn;
                const float* hf = (const float*)ch;
                #pragma unroll
                for (int j = 0; j < 32; ++j) {
                    const float hv = hf[j];
                    ar += wr[j] * hv; az += wz[j] * hv; an += wn[j] * hv;
                }
                const float gir = bf2f(cS), giz = bf2f(c32), gin = bf2f(c64);
                const float rg = sigm(gir + ar);
                const float zg = sigm(giz + az);
                const float ng = tanhx(gin + rg * an);
                const float hv2 = (1.f - zg) * ng + zg * h_own;
                Hb[(size_t)n * 32 + s] = hv2;
                float red = hv2 * wfcs;
                red += __shfl_xor(red, 16); red += __shfl_xor(red, 8);
                red += __shfl_xor(red, 4);  red += __shfl_xor(red, 2);
                red += __shfl_xor(red, 1);
                if (s == 0) out[(size_t)b * 65536 + (size_t)t * 1024 + n] = sigm(red + bfc);
                if (t == T_ - 1) out[OUT0 + (size_t)b * 32768 + (size_t)n * 32 + s] = hv2;
                cS = nS; c32 = n32; c64 = n64; h_own = nh_own;
                #pragma unroll
                for (int q = 0; q < 8; ++q) ch[q] = nh[q];
            }
        }
        bar4(barc, ep, tid);   // h complete before next step's phase A
    }
}

extern "C" void kernel_launch(void* const* d_in, const int* in_sizes, int n_in,
                              void* d_out, int out_size, void* d_ws, size_t ws_size,
                              hipStream_t stream)
{
    (void)in_sizes; (void)n_in; (void)out_size; (void)ws_size;
    const int* item_ids  = (const int*)d_in[0];
    const int* responses = (const int*)d_in[1];
    const void* adj      = d_in[2];
    const void* item_emb = d_in[3];
    const void* resp_emb = d_in[4];
    const void* w_in  = d_in[5];
    const void* b_in  = d_in[6];
    const void* w_out = d_in[7];
    const void* b_out = d_in[8];
    const void* in_a  = d_in[9];
    const void* out_a = d_in[10];
    const void* w_ih  = d_in[11];
    const void* w_hh  = d_in[12];
    const void* b_ih  = d_in[13];
    const void* b_hh  = d_in[14];
    const void* w_fc  = d_in[15];
    const void* b_fc  = d_in[16];
    float* ws = (float*)d_ws;
    float* out = (float*)d_out;

    k_detect<<<dim3(1), dim3(1024), 0, stream>>>((const unsigned int*)adj, ws);
    k_convert<<<dim3(64), dim3(256), 0, stream>>>(w_in, b_in, w_out, b_out, in_a, out_a,
                                                  w_ih, w_hh, b_ih, b_hh, w_fc, b_fc,
                                                  item_emb, resp_emb, ws);
    k_init<<<dim3(512), dim3(256), 0, stream>>>(ws);
    k_csc<<<dim3(1024), dim3(64), 0, stream>>>(adj, ws);

    void* kargs[] = { (void*)&item_ids, (void*)&responses, (void*)&ws, (void*)&out };
    (void)hipLaunchCooperativeKernel((const void*)gkt_main, dim3(256), dim3(512),
                                     kargs, 0, stream);
}

// Round 9
// 3899.847 us; speedup vs baseline: 3.3874x; 1.4326x over previous
//
#include <hip/hip_runtime.h>

// ---------------- problem constants ----------------
constexpr int N_ = 1024;   // ITEM_SIZE
constexpr int B_ = 64;     // BATCH
constexpr int T_ = 64;     // SEQ
constexpr int CAP = 128;   // max in-degree cap (mean ~33, max ~60)
constexpr size_t OUT0 = (size_t)B_ * T_ * N_;   // 4,194,304 f32 (outs), then B*N*S h (f32)

// ---------------- workspace layout (float offsets) — total ~9.7 MB ----------------
constexpr size_t WINTo  = 0;        // w_in^T  [j][i] 128*64 = 8192
constexpr size_t WOUTTo = 8192;     // w_out^T                 8192
constexpr size_t WIHTo  = 16384;    // w_ih^T  [j][g]  64*96 = 6144
constexpr size_t WHHo   = 22528;    // w_hh row-major          3072
constexpr size_t WFCo   = 25600;    // 32
constexpr size_t BINo   = 25632;    // 64
constexpr size_t BOUTo  = 25696;    // 64
constexpr size_t BIHo   = 25760;    // 96
constexpr size_t BHHo   = 25856;    // 96
constexpr size_t BFCo   = 25952;    // 16 (1 used)
constexpr size_t INAo   = 25968;    // 1024
constexpr size_t OUTAo  = 26992;    // 1024
constexpr size_t CCNTo  = 28016;    // 1024 int (in-degree per node)
constexpr size_t DTFo   = 29040;    // 16 (dtype flag int)
constexpr size_t IEMo   = 29056;    // item_emb f32 32768
constexpr size_t REMo   = 61824;    // resp_emb f32 65536
constexpr size_t SUMEMBo= 127360;   // sum of item_emb over in-neighbors: 1024*32
constexpr size_t QCNTo  = 160128;   // 1024*4 ints: counts of cidx[v] entries < 256/512/768
constexpr size_t OMASKo = 164224;   // u64[1024][16]: omask[v] bit j = adj[v][j]  (32768 f slots)
constexpr size_t CIDXo  = 196992;   // 1024*128 int (CSC col lists, ascending)
constexpr size_t PARTo  = 328064;   // partial h-sums f32 [par2][b64][i128][sub4*32+lane32] = 2,097,152
constexpr size_t BARo   = 2425216;  // 64 ints: per-batch epoch barrier counters
// end = 2,425,280 floats ≈ 9.7 MB

// ---------------- LDS layout (dynamic, float offsets) ----------------
constexpr int LDSF_H   = 0;         // h block-range [256][32] f32 = 8192
constexpr int LDSF_GI  = 8192;      // gi [256][96] bf16 = 24576 ushort = 12288 f-slots
constexpr int LDSF_FEA = 20480;     // fea_stage [8][192] f32 = 1536
constexpr int LDSF_DL  = 22016;     // dlist 128 ints
constexpr int LDS_FLOATS = 22144;
constexpr int LDS_BYTES  = LDS_FLOATS * 4;   // 88,576 B -> 1 block/CU

// ---------------- helpers ----------------
__device__ __forceinline__ float bf2f(unsigned short u) {
    union { unsigned int i; float f; } x; x.i = ((unsigned int)u) << 16; return x.f;
}
__device__ __forceinline__ unsigned short f2bf(float f) {
    union { float f; unsigned int u; } x; x.f = f;
    unsigned int u = x.u;
    return (unsigned short)((u + 0x7fffu + ((u >> 16) & 1u)) >> 16);  // RNE
}
__device__ __forceinline__ float sigm(float x) { return 1.f / (1.f + __expf(-x)); }
__device__ __forceinline__ float tanhx(float x) {
    x = fminf(15.f, fmaxf(-15.f, x));
    float e = __expf(2.f * x);
    return (e - 1.f) / (e + 1.f);
}
__device__ __forceinline__ float ldg_any(const void* p, int i, int isbf) {
    return isbf ? bf2f(((const unsigned short*)p)[i]) : ((const float*)p)[i];
}

// 4-block per-batch epoch barrier (leading __syncthreads drains all waves' stores — round-8 fix)
__device__ __forceinline__ void bar4(int* c, int& ep, int tid) {
    __syncthreads();
    if (tid == 0) {
        __threadfence();
        __hip_atomic_fetch_add(c, 1, __ATOMIC_RELEASE, __HIP_MEMORY_SCOPE_AGENT);
        const int target = 4 * (++ep);
        while (__hip_atomic_load(c, __ATOMIC_ACQUIRE, __HIP_MEMORY_SCOPE_AGENT) < target)
            __builtin_amdgcn_s_sleep(2);
        __threadfence();
    } else {
        ++ep;
    }
    __syncthreads();
}

// ---------------- prep: detect input float dtype from adj bit patterns ----------------
__global__ void k_detect(const unsigned int* __restrict__ adjw, float* __restrict__ ws)
{
    __shared__ int f;
    if (threadIdx.x == 0) f = 0;
    __syncthreads();
    int local = 0;
    for (int i = threadIdx.x; i < 524288; i += blockDim.x) {
        unsigned int w = adjw[i];
        if ((w & 0xFFFFu) == 0x3F80u) local = 1;
    }
    if (local) atomicOr(&f, 1);
    __syncthreads();
    if (threadIdx.x == 0) ((int*)(ws + DTFo))[0] = f;
}

// ---------------- prep: convert/pack weights -> f32 ----------------
__global__ void k_convert(const void* __restrict__ w_in,  const void* __restrict__ b_in,
                          const void* __restrict__ w_out, const void* __restrict__ b_out,
                          const void* __restrict__ in_a,  const void* __restrict__ out_a,
                          const void* __restrict__ w_ih,  const void* __restrict__ w_hh,
                          const void* __restrict__ b_ih,  const void* __restrict__ b_hh,
                          const void* __restrict__ w_fc,  const void* __restrict__ b_fc,
                          const void* __restrict__ item_emb, const void* __restrict__ resp_emb,
                          float* __restrict__ ws)
{
    const int isbf = ((const int*)(ws + DTFo))[0];
    const int tg  = blockIdx.x * blockDim.x + threadIdx.x;
    const int tot = gridDim.x * blockDim.x;
    for (int f = tg; f < 8192; f += tot) {
        int i = f & 63, j = f >> 6;
        ws[WINTo + f]  = ldg_any(w_in , i * 128 + j, isbf);
        ws[WOUTTo + f] = ldg_any(w_out, i * 128 + j, isbf);
    }
    for (int f = tg; f < 6144; f += tot) {
        int g = f % 96, j = f / 96;
        ws[WIHTo + f] = ldg_any(w_ih, g * 64 + j, isbf);
    }
    for (int f = tg; f < 3072; f += tot) ws[WHHo + f] = ldg_any(w_hh, f, isbf);
    for (int f = tg; f < 32;   f += tot) ws[WFCo + f] = ldg_any(w_fc, f, isbf);
    for (int f = tg; f < 64;   f += tot) { ws[BINo + f] = ldg_any(b_in, f, isbf); ws[BOUTo + f] = ldg_any(b_out, f, isbf); }
    for (int f = tg; f < 96;   f += tot) { ws[BIHo + f] = ldg_any(b_ih, f, isbf); ws[BHHo + f] = ldg_any(b_hh, f, isbf); }
    if (tg == 0) ws[BFCo] = ldg_any(b_fc, 0, isbf);
    for (int f = tg; f < 1024; f += tot) { ws[INAo + f] = ldg_any(in_a, f, isbf); ws[OUTAo + f] = ldg_any(out_a, f, isbf); }
    for (int f = tg; f < 32768; f += tot) ws[IEMo + f] = ldg_any(item_emb, f, isbf);
    for (int f = tg; f < 65536; f += tot) ws[REMo + f] = ldg_any(resp_emb, f, isbf);
}

// ---------------- prep: build CSC adjacency + quarter boundaries ----------------
__global__ void k_csc(const void* __restrict__ adj, float* __restrict__ ws)
{
    const int isbf = ((const int*)(ws + DTFo))[0];
    const int v = blockIdx.x;
    const int lane = threadIdx.x;
    int* ccnt = (int*)(ws + CCNTo);
    int* cidx = (int*)(ws + CIDXo);
    int* qcb  = (int*)(ws + QCNTo);
    int cnt = 0, c256 = 0, c512 = 0, c768 = 0;
    for (int ch = 0; ch < 16; ++ch) {
        int row = ch * 64 + lane;
        bool nz;
        if (isbf) nz = (((const unsigned short*)adj)[row * 1024 + v] != 0);
        else      nz = (((const float*)adj)[row * 1024 + v] != 0.f);
        unsigned long long m = __ballot(nz);
        int pos = cnt + __popcll(m & ((1ull << lane) - 1ull));
        if (nz && pos < CAP) cidx[v * CAP + pos] = row;
        cnt += __popcll(m);
        if (ch == 3)  c256 = cnt;
        if (ch == 7)  c512 = cnt;
        if (ch == 11) c768 = cnt;
    }
    if (lane == 0) {
        ccnt[v] = (cnt > CAP) ? CAP : cnt;
        qcb[v * 4 + 0] = (c256 > CAP) ? CAP : c256;
        qcb[v * 4 + 1] = (c512 > CAP) ? CAP : c512;
        qcb[v * 4 + 2] = (c768 > CAP) ? CAP : c768;
        qcb[v * 4 + 3] = 0;
    }
}

// ---------------- prep: out-neighbor bitmasks + static embedding sums ----------------
// omask[v] bit j = adj[v][j];  sumEmb[v] = sum_{u in cidx[v]} item_emb[u]
__global__ void k_emb(const void* __restrict__ adj, float* __restrict__ ws)
{
    const int isbf = ((const int*)(ws + DTFo))[0];
    const int v = blockIdx.x;
    const int lane = threadIdx.x;
    unsigned long long* om = (unsigned long long*)(ws + OMASKo);
    for (int w = 0; w < 16; ++w) {
        int col = w * 64 + lane;
        bool nz;
        if (isbf) nz = (((const unsigned short*)adj)[v * 1024 + col] != 0);
        else      nz = (((const float*)adj)[v * 1024 + col] != 0.f);
        unsigned long long m = __ballot(nz);
        if (lane == 0) om[v * 16 + w] = m;
    }
    const int cnt = ((const int*)(ws + CCNTo))[v];
    const int* cl = (const int*)(ws + CIDXo) + v * CAP;
    float acc = 0.f;
    for (int k = 0; k < cnt; ++k) {
        int u = cl[k];
        if (lane < 32) acc += ws[IEMo + u * 32 + lane];
    }
    if (lane < 32) ws[SUMEMBo + v * 32 + lane] = acc;
}

// ---------------- prep: zero barrier counters ----------------
__global__ void k_init(float* __restrict__ ws)
{
    if (threadIdx.x < 64) ((int*)(ws + BARo))[threadIdx.x] = 0;
}

// ---------------- main: 256 blocks = 4 per batch (cooperative) ----------------
// Block owns nodes [sub*256, sub*256+256): h + gi live in LDS for the whole kernel.
// Cross-block traffic per step = partial h-sums only (parity double-buffered, 1 bar4/step).
__global__ __launch_bounds__(512) void gkt_main(
    const int* __restrict__ item_ids, const int* __restrict__ responses,
    float* ws, float* __restrict__ out)
{
    extern __shared__ float smem[];
    float* h_lds = smem + LDSF_H;                         // [256][32]
    unsigned short* gi16 = (unsigned short*)(smem + LDSF_GI);  // [256][96] bf16
    float* fea_stage = smem + LDSF_FEA;                   // [8][192]
    int* dlist = (int*)(smem + LDSF_DL);                  // [128]

    const int tid  = threadIdx.x;
    const int lane = tid & 63;
    const int wave = tid >> 6;         // 0..7
    const int b    = blockIdx.x & 63;
    const int sub  = blockIdx.x >> 6;  // 0..3
    const int base = sub * 256;
    const int s    = lane & 31;
    const int gsel = (lane >> 5) & 1;

    int* barc = (int*)(ws + BARo) + b;
    const float* __restrict__ winT  = ws + WINTo;
    const float* __restrict__ woutT = ws + WOUTTo;
    const float* __restrict__ wihT  = ws + WIHTo;
    const float* __restrict__ whh   = ws + WHHo;
    const float* __restrict__ bin_f = ws + BINo;
    const float* __restrict__ bout_f= ws + BOUTo;
    const float* __restrict__ bih_f = ws + BIHo;
    const float* __restrict__ bhh_f = ws + BHHo;
    const float* __restrict__ ina_f = ws + INAo;
    const float* __restrict__ outa_f= ws + OUTAo;
    const float* __restrict__ iem   = ws + IEMo;
    const float* __restrict__ rem   = ws + REMo;
    const float* __restrict__ semb  = ws + SUMEMBo;
    const int* __restrict__ ccnt = (const int*)(ws + CCNTo);
    const int* __restrict__ cidx = (const int*)(ws + CIDXo);
    const int* __restrict__ qcb  = (const int*)(ws + QCNTo);
    const unsigned long long* __restrict__ omk = (const unsigned long long*)(ws + OMASKo);

    // init LDS: h = 0, gi = b_ih (bf16)
    for (int i = tid; i < 8192; i += 512) h_lds[i] = 0.f;
    for (int i = tid; i < 24576; i += 512) gi16[i] = f2bf(bih_f[i % 96]);

    // register-stationary GRU recurrent weights for this lane's state index s
    float wr[32], wz[32], wn[32];
    #pragma unroll
    for (int j = 0; j < 32; ++j) {
        wr[j] = whh[s * 32 + j];
        wz[j] = whh[(32 + s) * 32 + j];
        wn[j] = whh[(64 + s) * 32 + j];
    }
    const float bhr = bhh_f[s], bhz = bhh_f[32 + s], bhn = bhh_f[64 + s];
    const float wfcs = ws[WFCo + s];
    const float bfc  = ws[BFCo];
    __syncthreads();

    int ep = 0;
    const int gid = wave * 2 + gsel;   // 0..15, owns rows [gid*16, gid*16+16)

    for (int t = 0; t < T_; ++t) {
        const int item = item_ids[b * T_ + t];
        const int resp = responses[b * T_ + t];
        const int ndst = ccnt[item];
        if (tid < ndst) dlist[tid] = cidx[item * CAP + tid];
        __syncthreads();
        const float remv = (lane >= 32) ? rem[resp * 32 + (lane - 32)] : 0.f;

        float* Pbuf = ws + PARTo + ((size_t)(t & 1) * 64 + b) * 16384;   // [i][128]

        // ---- phase P: partial h-sums over own 256 rows, for every dst i ----
        for (int i = wave; i < ndst; i += 8) {
            const int v = dlist[i];
            const int k0 = (sub == 0) ? 0 : qcb[v * 4 + sub - 1];
            const int k1 = (sub == 3) ? ccnt[v] : qcb[v * 4 + sub];
            float acc = 0.f;
            for (int k = k0; k < k1; ++k) {
                const int ul = cidx[v * CAP + k] - base;
                if (lane < 32) acc += h_lds[ul * 32 + lane];
            }
            if (lane < 32) Pbuf[i * 128 + sub * 32 + lane] = acc;
        }
        bar4(barc, ep, tid);   // publish partials (the ONLY cross-block sync per step)

        // ---- phase A': FC + gi for dst nodes in OWN range ----
        float* fstage = fea_stage + wave * 192;
        for (int i = wave; i < ndst; i += 8) {
            const int v = dlist[i];
            if ((v >> 8) != sub) continue;           // wave-uniform skip
            const int vl = v & 255;
            float own, agg;
            if (lane < 32) {
                own = h_lds[vl * 32 + lane];
                const float* pp = Pbuf + i * 128;
                agg = pp[lane] + pp[32 + lane] + pp[64 + lane] + pp[96 + lane];
            } else {
                const int j = lane - 32;
                own = (v == item) ? remv : iem[v * 32 + j];
                const bool hasitem = (omk[item * 16 + (v >> 6)] >> (v & 63)) & 1ull;
                agg = semb[v * 32 + j] + (hasitem ? (remv - iem[item * 32 + j]) : 0.f);
            }
            fstage[lane]      = own;
            fstage[64 + lane] = agg;
            float ain = 0.f, aout = 0.f;
            const float4* f4p = (const float4*)fstage;
            #pragma unroll 8
            for (int c = 0; c < 32; ++c) {
                const float4 f = f4p[c];
                ain  += f.x * winT [(4*c+0)*64 + lane] + f.y * winT [(4*c+1)*64 + lane]
                      + f.z * winT [(4*c+2)*64 + lane] + f.w * winT [(4*c+3)*64 + lane];
                aout += f.x * woutT[(4*c+0)*64 + lane] + f.y * woutT[(4*c+1)*64 + lane]
                      + f.z * woutT[(4*c+2)*64 + lane] + f.w * woutT[(4*c+3)*64 + lane];
            }
            ain  += bin_f[lane];
            aout += bout_f[lane];
            const float dstv = outa_f[v] * aout + ina_f[v] * ain;
            fstage[128 + lane] = dstv;
            float g0 = bih_f[lane];
            float g1 = (lane < 32) ? bih_f[64 + lane] : 0.f;
            const float4* d4p = (const float4*)(fstage + 128);
            #pragma unroll 8
            for (int c = 0; c < 16; ++c) {
                const float4 dv = d4p[c];
                g0 += dv.x * wihT[(4*c+0)*96 + lane] + dv.y * wihT[(4*c+1)*96 + lane]
                    + dv.z * wihT[(4*c+2)*96 + lane] + dv.w * wihT[(4*c+3)*96 + lane];
                if (lane < 32) {
                    g1 += dv.x * wihT[(4*c+0)*96 + 64 + lane] + dv.y * wihT[(4*c+1)*96 + 64 + lane]
                        + dv.z * wihT[(4*c+2)*96 + 64 + lane] + dv.w * wihT[(4*c+3)*96 + 64 + lane];
                }
            }
            gi16[vl * 96 + lane] = f2bf(g0);
            if (lane < 32) gi16[vl * 96 + 64 + lane] = f2bf(g1);
        }
        __syncthreads();   // gi_lds visible to phase B

        // ---- phase B: GRU on own rows [gid*16, gid*16+16), all LDS ----
        {
            int nl = gid * 16;
            unsigned short cS = gi16[nl * 96 + s], c32 = gi16[nl * 96 + 32 + s], c64 = gi16[nl * 96 + 64 + s];
            const float4* hrow = (const float4*)(h_lds + nl * 32);
            float4 ch[8];
            #pragma unroll
            for (int q = 0; q < 8; ++q) ch[q] = hrow[q];
            float h_own = h_lds[nl * 32 + s];

            for (int i = 0; i < 16; ++i, ++nl) {
                unsigned short nS = 0, n32 = 0, n64 = 0;
                float4 nh[8];
                float nh_own = 0.f;
                if (i < 15) {
                    nS  = gi16[(nl + 1) * 96 + s];
                    n32 = gi16[(nl + 1) * 96 + 32 + s];
                    n64 = gi16[(nl + 1) * 96 + 64 + s];
                    const float4* hnx = (const float4*)(h_lds + (nl + 1) * 32);
                    #pragma unroll
                    for (int q = 0; q < 8; ++q) nh[q] = hnx[q];
                    nh_own = h_lds[(nl + 1) * 32 + s];
                }
                float ar = bhr, az = bhz, an = bhn;
                const float* hf = (const float*)ch;
                #pragma unroll
                for (int j = 0; j < 32; ++j) {
                    const float hv = hf[j];
                    ar += wr[j] * hv; az += wz[j] * hv; an += wn[j] * hv;
                }
                const float gir = bf2f(cS), giz = bf2f(c32), gin = bf2f(c64);
                const float rg = sigm(gir + ar);
                const float zg = sigm(giz + az);
                const float ng = tanhx(gin + rg * an);
                const float hv2 = (1.f - zg) * ng + zg * h_own;
                h_lds[nl * 32 + s] = hv2;
                float red = hv2 * wfcs;
                red += __shfl_xor(red, 16); red += __shfl_xor(red, 8);
                red += __shfl_xor(red, 4);  red += __shfl_xor(red, 2);
                red += __shfl_xor(red, 1);
                const int n = base + nl;
                if (s == 0) out[(size_t)b * 65536 + (size_t)t * 1024 + n] = sigm(red + bfc);
                if (t == T_ - 1) out[OUT0 + (size_t)b * 32768 + (size_t)n * 32 + s] = hv2;
                cS = nS; c32 = n32; c64 = n64; h_own = nh_own;
                #pragma unroll
                for (int q = 0; q < 8; ++q) ch[q] = nh[q];
            }
        }
        __syncthreads();   // h_lds writes visible to next step's phase P (block-local)
    }
}

extern "C" void kernel_launch(void* const* d_in, const int* in_sizes, int n_in,
                              void* d_out, int out_size, void* d_ws, size_t ws_size,
                              hipStream_t stream)
{
    (void)in_sizes; (void)n_in; (void)out_size; (void)ws_size;
    const int* item_ids  = (const int*)d_in[0];
    const int* responses = (const int*)d_in[1];
    const void* adj      = d_in[2];
    const void* item_emb = d_in[3];
    const void* resp_emb = d_in[4];
    const void* w_in  = d_in[5];
    const void* b_in  = d_in[6];
    const void* w_out = d_in[7];
    const void* b_out = d_in[8];
    const void* in_a  = d_in[9];
    const void* out_a = d_in[10];
    const void* w_ih  = d_in[11];
    const void* w_hh  = d_in[12];
    const void* b_ih  = d_in[13];
    const void* b_hh  = d_in[14];
    const void* w_fc  = d_in[15];
    const void* b_fc  = d_in[16];
    float* ws = (float*)d_ws;
    float* out = (float*)d_out;

    (void)hipFuncSetAttribute((const void*)gkt_main,
                              hipFuncAttributeMaxDynamicSharedMemorySize, LDS_BYTES);

    k_detect<<<dim3(1), dim3(1024), 0, stream>>>((const unsigned int*)adj, ws);
    k_convert<<<dim3(64), dim3(256), 0, stream>>>(w_in, b_in, w_out, b_out, in_a, out_a,
                                                  w_ih, w_hh, b_ih, b_hh, w_fc, b_fc,
                                                  item_emb, resp_emb, ws);
    k_csc<<<dim3(1024), dim3(64), 0, stream>>>(adj, ws);
    k_emb<<<dim3(1024), dim3(64), 0, stream>>>(adj, ws);
    k_init<<<dim3(1), dim3(64), 0, stream>>>(ws);

    void* kargs[] = { (void*)&item_ids, (void*)&responses, (void*)&ws, (void*)&out };
    (void)hipLaunchCooperativeKernel((const void*)gkt_main, dim3(256), dim3(512),
                                     kargs, LDS_BYTES, stream);
}